// Round 3
// baseline (169.962 us; speedup 1.0000x reference)
//
#include <hip/hip_runtime.h>

// Problem constants (fixed by the reference)
#define BB 1024
#define LL 256
#define DD 64
#define TDIM 100
#define NNODES 20000
#define HWORDS ((NNODES + 1) / 2)   // 10000 packed-u16 words

typedef _Float16 half8_t __attribute__((ext_vector_type(8)));
typedef float f32x4 __attribute__((ext_vector_type(4)));

// R6: the R0-VERIFIED kernel (one block = one (batch row, side) pair),
// byte-for-byte except __launch_bounds__ 2 -> 3. LDS = 42.4KB -> 3 blocks/CU
// fit; capping VGPR at ~170 raises occupancy 8 -> 12 waves/CU for the
// latency-exposed hist + cos phases. R4/R5's side-fusion failed correctness
// twice with bit-identical per-side math (race/miscompile suspected) and is
// abandoned pending evidence.
__global__ __launch_bounds__(256, 3) void tni_kernel(
    const int* __restrict__ src_ids, const int* __restrict__ dst_ids,
    const float* __restrict__ src_tm, const float* __restrict__ dst_tm,
    const float* __restrict__ node_tm,
    const float* __restrict__ w_time, const float* __restrict__ b_time,
    const float* __restrict__ w_ts, const float* __restrict__ b_ts,
    const float* __restrict__ w1, const float* __restrict__ b1,
    const float* __restrict__ w2, const float* __restrict__ b2,
    float* __restrict__ out)
{
    // 40,960B union: [hist: 10000 u32] | [W2v: 8KB (2048 u32) + Gv: 32KB]
    __shared__ unsigned int uS[10240];
    __shared__ float wrv[TDIM], brv[TDIM], wtsv[TDIM]; // coeffs (revolutions)
    __shared__ float w1v[DD], b1v[DD];

    unsigned int* hist = uS;
    half8_t* W2v = (half8_t*)uS;             // [DD*8], valid after hist phase
    half8_t* Gv  = (half8_t*)(uS + 2048);    // [LL*8]

    const int t    = threadIdx.x;
    const int b    = blockIdx.x >> 1;
    const int side = blockIdx.x & 1;

    // ---- per-thread inputs (issued early, coalesced) ----
    const int   sid   = src_ids[b*LL + t];
    const int   did   = dst_ids[b*LL + t];
    const float my_tm = side ? dst_tm[b*LL + t] : src_tm[b*LL + t];

    // prefetch w2 into registers; LDS write deferred until hist region frees
    float w2r[16];
    #pragma unroll
    for (int i = 0; i < 16; ++i) w2r[i] = w2[t + 256*i];

    if (t < TDIM) {
        const float inv2pi = 0.15915494309189535f;   // v_cos_f32 takes revolutions
        wrv[t]  = w_time[t] * inv2pi;
        brv[t]  = b_time[t] * inv2pi;
        wtsv[t] = w_ts[t];
    }
    if (t < DD) {
        w1v[t] = w1[t];
        b1v[t] = b1[t];
    }

    // ---- counts via packed-u16 histogram, clears limited to touched words ----
    const int sw = sid >> 1, ssh = (sid & 1) * 16;
    const int dw = did >> 1, dsh = (did & 1) * 16;
    const int myw  = side ? dw  : sw;
    const int mysh = side ? dsh : ssh;
    const int my_id = side ? did : sid;

    // epoch A: histogram of the src row -> count of my_id in src row (c1)
    hist[sw] = 0; hist[dw] = 0;
    __syncthreads();
    if (sid) atomicAdd(&hist[sw], 1u << ssh);
    __syncthreads();
    unsigned c1 = (hist[myw] >> mysh) & 0xffffu;
    __syncthreads();
    // epoch B: histogram of the dst row -> count of my_id in dst row (c2)
    hist[sw] = 0; hist[dw] = 0;
    __syncthreads();
    if (did) atomicAdd(&hist[dw], 1u << dsh);
    __syncthreads();
    unsigned c2 = (hist[myw] >> mysh) & 0xffffu;
    if (my_id == 0) { c1 = 0; c2 = 0; }   // padding id -> zero count (mask)
    __syncthreads();                       // hist reads done; region reusable

    // ---- time weight: sigmoid(cos(td*w+b) @ w_ts + b_ts) ----
    float td = node_tm[b] - my_tm;
    float z  = b_ts[0];
    #pragma unroll 4
    for (int k = 0; k < TDIM; ++k) {
        float r = fmaf(td, wrv[k], brv[k]);
        r -= floorf(r);                               // reduce to [0,1) revolutions
        z = fmaf(__builtin_amdgcn_cosf(r), wtsv[k], z);
    }
    float ee  = __builtin_amdgcn_exp2f(-1.44269504f * z);  // exp(-z)
    float wgt = __builtin_amdgcn_rcpf(1.0f + ee);          // sigmoid(z)
    float c1w = (float)c1 * wgt;
    float c2w = (float)c2 * wgt;

    // ---- stage w2 (from regs) -> W2v = w2^T rows [d][e] fp16, swizzled ----
    {
        _Float16* w2s = (_Float16*)W2v;
        #pragma unroll
        for (int i = 0; i < 16; ++i) {
            int idx = t + 256*i;            // 0..4095
            int e = idx >> 6, d = idx & 63;
            int chunk = (e >> 3) ^ (d & 7); // XOR swizzle on 16B chunks within a row
            w2s[d*64 + (chunk << 3) + (e & 7)] = (_Float16)w2r[i];
        }
    }

    // ---- g[e] = relu(c1w*w1+b1) + relu(c2w*w1+b1), fp16 into A-fragment LDS ----
    #pragma unroll
    for (int c = 0; c < 8; ++c) {
        half8_t h;
        #pragma unroll
        for (int j = 0; j < 8; ++j) {
            float w1e = w1v[c*8 + j], b1e = b1v[c*8 + j];
            float g = fmaxf(fmaf(c1w, w1e, b1e), 0.f)
                    + fmaxf(fmaf(c2w, w1e, b1e), 0.f);
            h[j] = (_Float16)g;
        }
        Gv[t*8 + (c ^ (t & 7))] = h;      // row t, swizzled chunk
    }
    __syncthreads();

    // ---- MFMA: [256 x 64] x [64 x 64], wave w owns rows 64w..64w+63 ----
    const int w    = t >> 6;
    const int l    = t & 63;
    const int quad = l >> 4;
    const int lr   = l & 15;

    f32x4 acc[4][4];
    #pragma unroll
    for (int mt = 0; mt < 4; ++mt)
        #pragma unroll
        for (int nt = 0; nt < 4; ++nt) {
            f32x4 zz = {0.f, 0.f, 0.f, 0.f};
            acc[mt][nt] = zz;
        }

    #pragma unroll
    for (int s = 0; s < 2; ++s) {         // K steps of 32
        const int c = s*4 + quad;         // logical 16B chunk (8 k's) this lane reads
        half8_t bfr[4], afr[4];
        #pragma unroll
        for (int nt = 0; nt < 4; ++nt) {  // B: lane holds B[k=quad*8+j][n=lane&15] = w2T row n
            int n = nt*16 + lr;
            bfr[nt] = W2v[n*8 + (c ^ (n & 7))];
        }
        #pragma unroll
        for (int mt = 0; mt < 4; ++mt) {  // A: lane holds A[m=lane&15][k=quad*8+j]
            int row = w*64 + mt*16 + lr;
            afr[mt] = Gv[row*8 + (c ^ (row & 7))];
        }
        #pragma unroll
        for (int mt = 0; mt < 4; ++mt)
            #pragma unroll
            for (int nt = 0; nt < 4; ++nt)
                acc[mt][nt] = __builtin_amdgcn_mfma_f32_16x16x32_f16(
                    afr[mt], bfr[nt], acc[mt][nt], 0, 0, 0);
    }

    // ---- epilogue: +2*b2, store fp32. C layout: col=lane&15, row=quad*4+reg ----
    float b2v[4];
    #pragma unroll
    for (int nt = 0; nt < 4; ++nt)
        b2v[nt] = 2.f * b2[nt*16 + lr];

    const int obase = side * (BB*LL*DD) + b * (LL*DD);
    #pragma unroll
    for (int mt = 0; mt < 4; ++mt) {
        #pragma unroll
        for (int r = 0; r < 4; ++r) {
            int pos = w*64 + mt*16 + quad*4 + r;
            #pragma unroll
            for (int nt = 0; nt < 4; ++nt) {
                out[obase + pos*DD + nt*16 + lr] = acc[mt][nt][r] + b2v[nt];
            }
        }
    }
}

extern "C" void kernel_launch(void* const* d_in, const int* in_sizes, int n_in,
                              void* d_out, int out_size, void* d_ws, size_t ws_size,
                              hipStream_t stream) {
    const int* src_ids = (const int*)d_in[0];
    const int* dst_ids = (const int*)d_in[1];
    const float* src_tm  = (const float*)d_in[2];
    const float* dst_tm  = (const float*)d_in[3];
    const float* node_tm = (const float*)d_in[4];
    // d_in[5] = num_nodes (fixed 20000; counts via LDS histogram)
    const float* w_time = (const float*)d_in[6];
    const float* b_time = (const float*)d_in[7];
    const float* w_ts   = (const float*)d_in[8];
    const float* b_ts   = (const float*)d_in[9];
    const float* w1     = (const float*)d_in[10];
    const float* b1     = (const float*)d_in[11];
    const float* w2     = (const float*)d_in[12];
    const float* b2     = (const float*)d_in[13];
    float* out = (float*)d_out;

    tni_kernel<<<dim3(BB*2), dim3(256), 0, stream>>>(
        src_ids, dst_ids, src_tm, dst_tm, node_tm,
        w_time, b_time, w_ts, b_ts, w1, b1, w2, b2, out);
}

// Round 4
// 169.305 us; speedup vs baseline: 1.0039x; 1.0039x over previous
//
#include <hip/hip_runtime.h>

// Problem constants (fixed by the reference)
#define BB 1024
#define LL 256
#define DD 64
#define TDIM 100

typedef _Float16 half8_t __attribute__((ext_vector_type(8)));
typedef float f32x4 __attribute__((ext_vector_type(4)));

// R7: one block = one batch row, both sides STRAIGHT-LINE (no unrolled side
// loop -- R4/R5's barrier-in-unrolled-loop structure failed twice and is the
// prime miscompile suspect; Gv is wave-private so no data race was possible).
// Each side gets its OWN G buffer (G0 aliases nothing live; G1 separate), so
// a single barrier separates ALL LDS staging (W2v, G0, G1) from ALL compute.
// The two MFMA passes share the W2v B-fragments (halves W2v LDS reads).
// Per-side arithmetic is bit-identical to the R6-verified kernel.
// LDS: uS 40KB = [hist 10000 u32 | W2v 8KB + G0 32KB] + G1 32KB + coeffs
//  = 75.4KB -> 2 blocks/CU.
__global__ __launch_bounds__(256, 2) void tni_kernel(
    const int* __restrict__ src_ids, const int* __restrict__ dst_ids,
    const float* __restrict__ src_tm, const float* __restrict__ dst_tm,
    const float* __restrict__ node_tm,
    const float* __restrict__ w_time, const float* __restrict__ b_time,
    const float* __restrict__ w_ts, const float* __restrict__ b_ts,
    const float* __restrict__ w1, const float* __restrict__ b1,
    const float* __restrict__ w2, const float* __restrict__ b2,
    float* __restrict__ out)
{
    __shared__ unsigned int uS[10240];                 // hist | {W2v, G0}
    __shared__ half8_t G1[LL*8];                       // 32KB, side-1 G
    __shared__ float wrv[TDIM], brv[TDIM], wtsv[TDIM]; // coeffs (revolutions)
    __shared__ float w1v[DD], b1v[DD];

    unsigned int* hist = uS;
    half8_t* W2v = (half8_t*)uS;             // [DD*8] = 8KB, after hist phase
    half8_t* G0  = (half8_t*)(uS + 2048);    // [LL*8] = 32KB

    const int t = threadIdx.x;
    const int b = blockIdx.x;

    // ---- per-thread inputs (issued early, coalesced) ----
    const int   sid  = src_ids[b*LL + t];
    const int   did  = dst_ids[b*LL + t];
    const float s_tm = src_tm[b*LL + t];
    const float d_tm = dst_tm[b*LL + t];
    const float ntm  = node_tm[b];

    // prefetch w2 into registers; LDS write deferred until hist region frees
    float w2r[16];
    #pragma unroll
    for (int i = 0; i < 16; ++i) w2r[i] = w2[t + 256*i];

    if (t < TDIM) {
        const float inv2pi = 0.15915494309189535f;   // v_cos_f32 takes revolutions
        wrv[t]  = w_time[t] * inv2pi;
        brv[t]  = b_time[t] * inv2pi;
        wtsv[t] = w_ts[t];
    }
    if (t < DD) { w1v[t] = w1[t]; b1v[t] = b1[t]; }

    // ---- counts via packed-u16 histogram: 2 epochs give all 4 counts ----
    const int sw = sid >> 1, ssh = (sid & 1) * 16;
    const int dw = did >> 1, dsh = (did & 1) * 16;

    // epoch A: src-row histogram -> c_ss (count of sid), c_ds (count of did)
    hist[sw] = 0; hist[dw] = 0;
    __syncthreads();
    if (sid) atomicAdd(&hist[sw], 1u << ssh);
    __syncthreads();
    unsigned c_ss = (hist[sw] >> ssh) & 0xffffu;
    unsigned c_ds = (hist[dw] >> dsh) & 0xffffu;
    __syncthreads();
    // epoch B: dst-row histogram -> c_sd, c_dd
    hist[sw] = 0; hist[dw] = 0;
    __syncthreads();
    if (did) atomicAdd(&hist[dw], 1u << dsh);
    __syncthreads();
    unsigned c_sd = (hist[sw] >> ssh) & 0xffffu;
    unsigned c_dd = (hist[dw] >> dsh) & 0xffffu;
    if (sid == 0) { c_ss = 0; c_sd = 0; }  // padding id -> zero count
    if (did == 0) { c_ds = 0; c_dd = 0; }
    __syncthreads();                        // hist reads done; uS reusable

    // ---- stage w2 (from regs) -> W2v = w2^T rows [d][e] fp16, swizzled ----
    {
        _Float16* w2s = (_Float16*)W2v;
        #pragma unroll
        for (int i = 0; i < 16; ++i) {
            int idx = t + 256*i;            // 0..4095
            int e = idx >> 6, d = idx & 63;
            int chunk = (e >> 3) ^ (d & 7); // XOR swizzle on 16B chunks in a row
            w2s[d*64 + (chunk << 3) + (e & 7)] = (_Float16)w2r[i];
        }
    }

    // ---- dual time weight: sigmoid(cos(td*w+b) @ w_ts + b_ts) ----
    const float td_s = ntm - s_tm;
    const float td_d = ntm - d_tm;
    float zs = b_ts[0], zd = zs;
    #pragma unroll 4
    for (int k = 0; k < TDIM; ++k) {
        float wk = wrv[k], bk = brv[k], ck = wtsv[k];
        float rs = fmaf(td_s, wk, bk); rs -= floorf(rs);   // [0,1) revolutions
        zs = fmaf(__builtin_amdgcn_cosf(rs), ck, zs);
        float rd = fmaf(td_d, wk, bk); rd -= floorf(rd);
        zd = fmaf(__builtin_amdgcn_cosf(rd), ck, zd);
    }
    const float wgt_s = __builtin_amdgcn_rcpf(
        1.0f + __builtin_amdgcn_exp2f(-1.44269504f * zs));   // sigmoid
    const float wgt_d = __builtin_amdgcn_rcpf(
        1.0f + __builtin_amdgcn_exp2f(-1.44269504f * zd));

    const float c1w0 = (float)c_ss * wgt_s, c2w0 = (float)c_sd * wgt_s;
    const float c1w1 = (float)c_ds * wgt_d, c2w1 = (float)c_dd * wgt_d;

    // ---- G0/G1: g[e] = relu(c1w*w1+b1) + relu(c2w*w1+b1), fp16, swizzled ----
    #pragma unroll
    for (int c = 0; c < 8; ++c) {
        half8_t h0, h1;
        #pragma unroll
        for (int j = 0; j < 8; ++j) {
            float w1e = w1v[c*8 + j], b1e = b1v[c*8 + j];
            h0[j] = (_Float16)(fmaxf(fmaf(c1w0, w1e, b1e), 0.f)
                             + fmaxf(fmaf(c2w0, w1e, b1e), 0.f));
            h1[j] = (_Float16)(fmaxf(fmaf(c1w1, w1e, b1e), 0.f)
                             + fmaxf(fmaf(c2w1, w1e, b1e), 0.f));
        }
        int gi = t*8 + (c ^ (t & 7));
        G0[gi] = h0;
        G1[gi] = h1;
    }
    __syncthreads();   // ONE barrier: W2v + G0 + G1 all visible

    // ---- MFMA both sides, shared B-fragments (w2^T) ----
    const int wv   = t >> 6;     // wave owns output rows 64wv..64wv+63
    const int l    = t & 63;
    const int quad = l >> 4;
    const int lr   = l & 15;

    f32x4 acc0[4][4], acc1[4][4];
    #pragma unroll
    for (int mt = 0; mt < 4; ++mt)
        #pragma unroll
        for (int nt = 0; nt < 4; ++nt) {
            f32x4 zz = {0.f, 0.f, 0.f, 0.f};
            acc0[mt][nt] = zz;
            acc1[mt][nt] = zz;
        }

    #pragma unroll
    for (int s = 0; s < 2; ++s) {         // K steps of 32
        const int c = s*4 + quad;         // logical 16B chunk this lane reads
        half8_t bfr[4], afr0[4], afr1[4];
        #pragma unroll
        for (int nt = 0; nt < 4; ++nt) {  // B: lane holds B[k][n=lane&15]
            int n = nt*16 + lr;
            bfr[nt] = W2v[n*8 + (c ^ (n & 7))];
        }
        #pragma unroll
        for (int mt = 0; mt < 4; ++mt) {  // A: lane holds A[m=lane&15][k]
            int row = wv*64 + mt*16 + lr;
            int gi  = row*8 + (c ^ (row & 7));
            afr0[mt] = G0[gi];
            afr1[mt] = G1[gi];
        }
        #pragma unroll
        for (int mt = 0; mt < 4; ++mt)
            #pragma unroll
            for (int nt = 0; nt < 4; ++nt) {
                acc0[mt][nt] = __builtin_amdgcn_mfma_f32_16x16x32_f16(
                    afr0[mt], bfr[nt], acc0[mt][nt], 0, 0, 0);
                acc1[mt][nt] = __builtin_amdgcn_mfma_f32_16x16x32_f16(
                    afr1[mt], bfr[nt], acc1[mt][nt], 0, 0, 0);
            }
    }

    // ---- epilogues: +2*b2, fp32. C layout: col=lane&15, row=quad*4+reg ----
    float b2v[4];
    #pragma unroll
    for (int nt = 0; nt < 4; ++nt) b2v[nt] = 2.f * b2[nt*16 + lr];

    const int obase0 = b * (LL*DD);
    const int obase1 = (BB*LL*DD) + b * (LL*DD);
    #pragma unroll
    for (int mt = 0; mt < 4; ++mt) {
        #pragma unroll
        for (int r = 0; r < 4; ++r) {
            int po = (wv*64 + mt*16 + quad*4 + r) * DD;
            #pragma unroll
            for (int nt = 0; nt < 4; ++nt) {
                out[obase0 + po + nt*16 + lr] = acc0[mt][nt][r] + b2v[nt];
            }
            #pragma unroll
            for (int nt = 0; nt < 4; ++nt) {
                out[obase1 + po + nt*16 + lr] = acc1[mt][nt][r] + b2v[nt];
            }
        }
    }
}

extern "C" void kernel_launch(void* const* d_in, const int* in_sizes, int n_in,
                              void* d_out, int out_size, void* d_ws, size_t ws_size,
                              hipStream_t stream) {
    const int* src_ids = (const int*)d_in[0];
    const int* dst_ids = (const int*)d_in[1];
    const float* src_tm  = (const float*)d_in[2];
    const float* dst_tm  = (const float*)d_in[3];
    const float* node_tm = (const float*)d_in[4];
    // d_in[5] = num_nodes (fixed 20000; counts via LDS histogram)
    const float* w_time = (const float*)d_in[6];
    const float* b_time = (const float*)d_in[7];
    const float* w_ts   = (const float*)d_in[8];
    const float* b_ts   = (const float*)d_in[9];
    const float* w1     = (const float*)d_in[10];
    const float* b1     = (const float*)d_in[11];
    const float* w2     = (const float*)d_in[12];
    const float* b2     = (const float*)d_in[13];
    float* out = (float*)d_out;

    tni_kernel<<<dim3(BB), dim3(256), 0, stream>>>(
        src_ids, dst_ids, src_tm, dst_tm, node_tm,
        w_time, b_time, w_ts, b_ts, w1, b1, w2, b2, out);
}